// Round 8
// baseline (233.634 us; speedup 1.0000x reference)
//
#include <hip/hip_runtime.h>
#include <hip/hip_bf16.h>
#include <stdint.h>

// Masked self-attention (round 8): consolidation of measured-best parts.
// - qkv_8phase: combined 768-block dispatch (3 exact CU rounds) WITH T1
//   XCD swizzle (round-5 A/B: 146.9 -> 135.9 us).
// - scores_8ph / pv_8ph: round-4 linear grids, NO swizzle (round-5 A/B:
//   swizzle cost ~11 us here).
// - softmax: round-5 form (loads trimmed to valid 256-aligned prefix).
// - gemm8_core byte-identical to the rounds-3..7 verified core.

#define BATCH 16
#define SEQL  1024
#define IMG   256
#define EMB   1024
#define MTOT  (BATCH * SEQL)   // 16384

typedef __attribute__((ext_vector_type(8))) short short8;
typedef __attribute__((ext_vector_type(8))) unsigned short u16x8;
typedef __attribute__((ext_vector_type(4))) unsigned short u16x4;
typedef __attribute__((ext_vector_type(4))) float f32x4;

__device__ __forceinline__ void gload_lds16(const void* g, void* l) {
    __builtin_amdgcn_global_load_lds(
        (const __attribute__((address_space(1))) void*)g,
        (__attribute__((address_space(3))) void*)l, 16, 0, 0);
}

__device__ __forceinline__ unsigned short f2bf(float f) {
    uint32_t u = __float_as_uint(f);
    u += 0x7FFFu + ((u >> 16) & 1u);
    return (unsigned short)(u >> 16);
}

// ===========================================================================
// 8-phase 256x256 GEMM core (verified rounds 3-7).  C = A(256 x 64*KT) * B^T,
// A/B row-major, row stride 2048 B.  8 waves (2M x 4N), wave tile 128x64,
// acc[8][4] f32x4.  LDS 128 KiB double-buffered, XOR-swizzled; counted
// vmcnt(2) at tile boundary only; raw s_barrier; setprio around MFMA.
// SWAP=true computes mfma(B,A): C-frag rows = lane&15 (M), cols =
// (lane>>4)*4+r (N) -> packed stores along N.
// ===========================================================================
template<bool SWAP>
__device__ __forceinline__ void gemm8_core(
    const char* __restrict__ Ab, const char* __restrict__ Bb,
    char* lds, const int KT, f32x4 acc[8][4])
{
    const int tid  = threadIdx.x;
    const int lane = tid & 63;
    const int wv   = tid >> 6;
    const int wr   = wv >> 2, wc = wv & 3;
    const int lr   = lane & 15, kh = lane >> 4;

    const int sw  = (lr & 7) << 4;
    const int cb0 = (kh * 16) ^ sw;
    const int cb1 = (64 + kh * 16) ^ sw;

    const size_t psStage = (size_t)(wv * 16 + (lane >> 3)) * 2048
                         + (size_t)((((lane & 7) ^ (lane >> 3))) << 4);

    auto stageA = [&](int tt, int h) {
        if (tt < KT) {
            const char* s = Ab + psStage + (size_t)h * 262144 + (size_t)tt * 128;
            char* d = lds + (tt & 1) * 65536 + h * 16384 + wv * 2048;
            gload_lds16(s, d);
            gload_lds16(s + 16384, d + 1024);
        }
    };
    auto stageB = [&](int tt, int h) {
        if (tt < KT) {
            const char* s = Bb + psStage + (size_t)h * 262144 + (size_t)tt * 128;
            char* d = lds + (tt & 1) * 65536 + 32768 + h * 16384 + wv * 2048;
            gload_lds16(s, d);
            gload_lds16(s + 16384, d + 1024);
        }
    };

    stageA(0, 0); stageA(0, 1); stageB(0, 0); stageB(0, 1); stageA(1, 0);
    asm volatile("s_waitcnt vmcnt(2)" ::: "memory");
    __builtin_amdgcn_s_barrier();

    short8 af[4][2];
    short8 bf[4][2];

    const int bh   = wc >> 1;
    const int brow = (wc & 1) * 64 + lr;

    #pragma unroll 1
    for (int t = 0; t < KT; ++t) {
        const int d = t & 1;
        const char* aBase = lds + d * 65536 + wr * 16384 + lr * 128;
        const char* bBase = lds + d * 65536 + 32768 + bh * 16384 + brow * 128;

        auto loadA = [&](int IQ) {
            #pragma unroll
            for (int ii = 0; ii < 4; ++ii) {
                af[ii][0] = *(const short8*)(aBase + (IQ * 4 + ii) * 2048 + cb0);
                af[ii][1] = *(const short8*)(aBase + (IQ * 4 + ii) * 2048 + cb1);
            }
        };
        auto loadB = [&](int JQ) {
            #pragma unroll
            for (int jj = 0; jj < 2; ++jj) {
                bf[JQ * 2 + jj][0] = *(const short8*)(bBase + (JQ * 2 + jj) * 2048 + cb0);
                bf[JQ * 2 + jj][1] = *(const short8*)(bBase + (JQ * 2 + jj) * 2048 + cb1);
            }
        };
        auto mfma16 = [&](int IQ, int JQ) {
            __builtin_amdgcn_s_barrier();
            __builtin_amdgcn_s_setprio(1);
            #pragma unroll
            for (int ii = 0; ii < 4; ++ii)
                #pragma unroll
                for (int jj = 0; jj < 2; ++jj)
                    #pragma unroll
                    for (int kk = 0; kk < 2; ++kk) {
                        f32x4& c = acc[IQ * 4 + ii][JQ * 2 + jj];
                        if (SWAP)
                            c = __builtin_amdgcn_mfma_f32_16x16x32_bf16(
                                bf[JQ * 2 + jj][kk], af[ii][kk], c, 0, 0, 0);
                        else
                            c = __builtin_amdgcn_mfma_f32_16x16x32_bf16(
                                af[ii][kk], bf[JQ * 2 + jj][kk], c, 0, 0, 0);
                    }
            __builtin_amdgcn_s_setprio(0);
        };

        loadA(0); loadB(0); stageA(t + 1, 1);
        mfma16(0, 0);
        __builtin_amdgcn_s_barrier();
        loadB(1); stageB(t + 1, 0);
        mfma16(0, 1);
        __builtin_amdgcn_s_barrier();
        loadA(1); stageB(t + 1, 1);
        mfma16(1, 1);
        __builtin_amdgcn_s_barrier();
        stageA(t + 2, 0);
        mfma16(1, 0);
        if (t < KT - 2) asm volatile("s_waitcnt vmcnt(2)" ::: "memory");
        else            asm volatile("s_waitcnt vmcnt(0)" ::: "memory");
        __builtin_amdgcn_s_barrier();
    }
}

// ---------------------------------------------------------------------------
// QKV projection, one 768-block dispatch (3 exact CU rounds) with T1 swizzle:
// nw = (f%8)*96 + f/8, decoded m-fastest so XCD-contiguous blocks share the
// (n0,z) weight panel.  z<2 -> Q/K row-major bf16 (SWAP); z=2 -> Vt[b][d][s]
// (non-SWAP, packed 8 B stores along s).
// ---------------------------------------------------------------------------
__global__ void __launch_bounds__(512, 1) qkv_8phase(
    const unsigned short* __restrict__ Xb, const unsigned short* __restrict__ Wb,
    const float* __restrict__ bq, const float* __restrict__ bk,
    const float* __restrict__ bv,
    unsigned short* __restrict__ Qb, unsigned short* __restrict__ Kb,
    unsigned short* __restrict__ Vtb)
{
    extern __shared__ char lds[];
    const unsigned f  = blockIdx.x + 64u * blockIdx.y + 256u * blockIdx.z;
    const unsigned nw = (f & 7u) * 96u + (f >> 3);          // bijective, 768%8==0
    const int m0 = (int)(nw & 63u) * 256;
    const int n0 = (int)((nw >> 6) & 3u) * 256;
    const int z  = (int)(nw >> 8);

    const char* Ab = (const char*)Xb + (size_t)m0 * 2048;
    const char* Bb = (const char*)(Wb + ((size_t)z << 20)) + (size_t)n0 * 2048;

    const int lane = threadIdx.x & 63, wv = threadIdx.x >> 6;
    const int wr = wv >> 2, wc = wv & 3, lr = lane & 15, kh = lane >> 4;

    if (z < 2) {
        f32x4 acc[8][4] = {};
        gemm8_core<true>(Ab, Bb, lds, 16, acc);

        unsigned short* Y = z ? Kb : Qb;
        const float* bias = z ? bk : bq;
        #pragma unroll
        for (int i = 0; i < 8; ++i) {
            const int grow = m0 + wr * 128 + i * 16 + lr;
            #pragma unroll
            for (int j = 0; j < 4; ++j) {
                const int gc0 = n0 + wc * 64 + j * 16 + kh * 4;
                const float4 bb = *(const float4*)(bias + gc0);
                u16x4 o;
                o[0] = f2bf(acc[i][j][0] + bb.x);
                o[1] = f2bf(acc[i][j][1] + bb.y);
                o[2] = f2bf(acc[i][j][2] + bb.z);
                o[3] = f2bf(acc[i][j][3] + bb.w);
                *(u16x4*)(Y + (size_t)grow * EMB + gc0) = o;
            }
        }
    } else {
        f32x4 acc[8][4] = {};
        gemm8_core<false>(Ab, Bb, lds, 16, acc);

        #pragma unroll
        for (int i = 0; i < 8; ++i) {
            const int srow0 = m0 + wr * 128 + i * 16 + kh * 4;
            const int b = srow0 >> 10, s = srow0 & 1023;
            #pragma unroll
            for (int j = 0; j < 4; ++j) {
                const int dcol = n0 + wc * 64 + j * 16 + lr;
                const float bb = bv[dcol];
                u16x4 o;
                o[0] = f2bf(acc[i][j][0] + bb);
                o[1] = f2bf(acc[i][j][1] + bb);
                o[2] = f2bf(acc[i][j][2] + bb);
                o[3] = f2bf(acc[i][j][3] + bb);
                *(u16x4*)(Vtb + ((size_t)b << 20) + ((size_t)dcol << 10) + s) = o;
            }
        }
    }
}

// ---------------------------------------------------------------------------
// scores[b,q,k] = (Q.K)/32 fp32, 256^2 tiles, skip fully-masked (tj>ti).
// Linear grid (round-4 verified; swizzle measured harmful here).
// ---------------------------------------------------------------------------
__global__ void __launch_bounds__(512, 1) scores_8ph(
    const unsigned short* __restrict__ Qb, const unsigned short* __restrict__ Kb,
    float* __restrict__ sims)
{
    const int ti = blockIdx.x, tj = blockIdx.y, b = blockIdx.z;
    if (tj > ti) return;
    extern __shared__ char lds[];

    const size_t boff = (size_t)b << 20;
    const int m0 = ti * 256, n0 = tj * 256;
    const char* Ab = (const char*)(Qb + boff) + (size_t)m0 * 2048;
    const char* Bb = (const char*)(Kb + boff) + (size_t)n0 * 2048;

    f32x4 acc[8][4] = {};
    gemm8_core<true>(Ab, Bb, lds, 16, acc);

    float* S = sims + boff;
    const int lane = threadIdx.x & 63, wv = threadIdx.x >> 6;
    const int wr = wv >> 2, wc = wv & 3, lr = lane & 15, kh = lane >> 4;
    #pragma unroll
    for (int i = 0; i < 8; ++i) {
        const int q = m0 + wr * 128 + i * 16 + lr;
        #pragma unroll
        for (int j = 0; j < 4; ++j) {
            const int k0 = n0 + wc * 64 + j * 16 + kh * 4;
            float4 o;
            o.x = acc[i][j][0] * 0.03125f;
            o.y = acc[i][j][1] * 0.03125f;
            o.z = acc[i][j][2] * 0.03125f;
            o.w = acc[i][j][3] * 0.03125f;
            *(float4*)(S + (size_t)q * SEQL + k0) = o;
        }
    }
}

// ---------------------------------------------------------------------------
// Row softmax over valid prefix L = max(256, s+1); bf16 out zero-padded to
// Kt = max(256, 256*(s/256+1)).  Loads trimmed to c < Kt.
// ---------------------------------------------------------------------------
__global__ __launch_bounds__(256) void softmax_bf16(
    const float* __restrict__ sims, unsigned short* __restrict__ attnb)
{
    const int row = blockIdx.x;
    const int s   = row & (SEQL - 1);
    const int L   = (s + 1 > IMG) ? (s + 1) : IMG;
    const int Kt  = ((((s >> 8) + 1) << 8) > IMG) ? (((s >> 8) + 1) << 8) : IMG;

    const float* p = sims + (size_t)row * SEQL;
    const int tid = threadIdx.x, lane = tid & 63, wv = tid >> 6;
    const int c = tid * 4;
    float4 v = make_float4(0.f, 0.f, 0.f, 0.f);
    if (c < Kt) v = *(const float4*)(p + c);

    __shared__ float red[8];

    float m = -3.0e38f;
    if (c + 0 < L) m = fmaxf(m, v.x);
    if (c + 1 < L) m = fmaxf(m, v.y);
    if (c + 2 < L) m = fmaxf(m, v.z);
    if (c + 3 < L) m = fmaxf(m, v.w);
    #pragma unroll
    for (int off = 32; off > 0; off >>= 1) m = fmaxf(m, __shfl_xor(m, off));
    if (lane == 0) red[wv] = m;
    __syncthreads();
    m = fmaxf(fmaxf(red[0], red[1]), fmaxf(red[2], red[3]));

    const float e0 = (c + 0 < L) ? __expf(v.x - m) : 0.0f;
    const float e1 = (c + 1 < L) ? __expf(v.y - m) : 0.0f;
    const float e2 = (c + 2 < L) ? __expf(v.z - m) : 0.0f;
    const float e3 = (c + 3 < L) ? __expf(v.w - m) : 0.0f;
    float ssum = e0 + e1 + e2 + e3;
    #pragma unroll
    for (int off = 32; off > 0; off >>= 1) ssum += __shfl_xor(ssum, off);
    if (lane == 0) red[4 + wv] = ssum;
    __syncthreads();
    const float inv = 1.0f / (red[4] + red[5] + red[6] + red[7]);

    if (c < Kt) {
        u16x4 o;
        o[0] = f2bf(e0 * inv); o[1] = f2bf(e1 * inv);
        o[2] = f2bf(e2 * inv); o[3] = f2bf(e3 * inv);
        *(u16x4*)(attnb + (size_t)row * SEQL + c) = o;
    }
}

// ---------------------------------------------------------------------------
// out[b,q,d] = attn[b,q,:] . V[b,:,d] via B^T GEMM against Vt[b][d][k].
// 256^2 tiles, KT = (ti+1)*4.  Linear grid (round-4 verified form).
// ---------------------------------------------------------------------------
__global__ void __launch_bounds__(512, 1) pv_8ph(
    const unsigned short* __restrict__ attnb, const unsigned short* __restrict__ Vtb,
    float* __restrict__ out)
{
    const int ti = blockIdx.x, tj = blockIdx.y, b = blockIdx.z;
    extern __shared__ char lds[];

    const size_t boff = (size_t)b << 20;
    const int m0 = ti * 256, n0 = tj * 256;
    const int KT = (ti + 1) * 4;

    const char* Ab = (const char*)(attnb + boff) + (size_t)m0 * 2048;
    const char* Bb = (const char*)(Vtb + boff) + (size_t)n0 * 2048;

    f32x4 acc[8][4] = {};
    gemm8_core<true>(Ab, Bb, lds, KT, acc);

    float* O = out + boff;
    const int lane = threadIdx.x & 63, wv = threadIdx.x >> 6;
    const int wr = wv >> 2, wc = wv & 3, lr = lane & 15, kh = lane >> 4;
    #pragma unroll
    for (int i = 0; i < 8; ++i) {
        const int q = m0 + wr * 128 + i * 16 + lr;
        #pragma unroll
        for (int j = 0; j < 4; ++j) {
            const int d0 = n0 + wc * 64 + j * 16 + kh * 4;
            *(float4*)(O + (size_t)q * EMB + d0) = *(const float4*)&acc[i][j];
        }
    }
}

// ---------------------------------------------------------------------------
// fp32 -> bf16 conversion of x and the three weight matrices.
// ---------------------------------------------------------------------------
__global__ __launch_bounds__(256) void convert_bf16(
    const float* __restrict__ x,
    const float* __restrict__ Wq, const float* __restrict__ Wk,
    const float* __restrict__ Wv,
    unsigned short* __restrict__ Xb, unsigned short* __restrict__ Wb)
{
    const size_t NE  = (size_t)MTOT * EMB;
    const size_t idx = ((size_t)blockIdx.x * 256 + threadIdx.x) * 8;
    const float* src; unsigned short* dst; size_t off;
    if (idx < NE) { src = x; dst = Xb; off = idx; }
    else {
        const size_t w = idx - NE;
        const int wi = (int)(w >> 20);
        off = w & 0xFFFFFu;
        src = (wi == 0) ? Wq : (wi == 1) ? Wk : Wv;
        dst = Wb + ((size_t)wi << 20);
    }
    const float4 a = *(const float4*)(src + off);
    const float4 b = *(const float4*)(src + off + 4);
    u16x8 o;
    o[0] = f2bf(a.x); o[1] = f2bf(a.y); o[2] = f2bf(a.z); o[3] = f2bf(a.w);
    o[4] = f2bf(b.x); o[5] = f2bf(b.y); o[6] = f2bf(b.z); o[7] = f2bf(b.w);
    *(u16x8*)(dst + off) = o;
}

// ---------------------------------------------------------------------------
extern "C" void kernel_launch(void* const* d_in, const int* in_sizes, int n_in,
                              void* d_out, int out_size, void* d_ws, size_t ws_size,
                              hipStream_t stream)
{
    const float* x  = (const float*)d_in[0];
    const float* Wq = (const float*)d_in[1];
    const float* bq = (const float*)d_in[2];
    const float* Wk = (const float*)d_in[3];
    const float* bk = (const float*)d_in[4];
    const float* Wv = (const float*)d_in[5];
    const float* bv = (const float*)d_in[6];

    const size_t NE = (size_t)MTOT * EMB;
    unsigned short* base  = (unsigned short*)d_ws;
    unsigned short* Qb    = base;                  // NE bf16
    unsigned short* Kb    = base + NE;             // NE
    unsigned short* Vtb   = base + 2 * NE;         // NE
    unsigned short* Xb    = base + 3 * NE;         // NE (dead after qkv)
    unsigned short* attnb = base + 3 * NE;         // reuses Xb region
    unsigned short* Wb    = base + 4 * NE;         // 3 * 2^20
    float* sims = (float*)d_out;

    hipFuncSetAttribute(reinterpret_cast<const void*>(qkv_8phase),
                        hipFuncAttributeMaxDynamicSharedMemorySize, 131072);
    hipFuncSetAttribute(reinterpret_cast<const void*>(scores_8ph),
                        hipFuncAttributeMaxDynamicSharedMemorySize, 131072);
    hipFuncSetAttribute(reinterpret_cast<const void*>(pv_8ph),
                        hipFuncAttributeMaxDynamicSharedMemorySize, 131072);

    convert_bf16<<<dim3((unsigned)((NE + 3u * (1u << 20)) / 2048)), 256, 0, stream>>>(
        x, Wq, Wk, Wv, Xb, Wb);

    qkv_8phase<<<dim3(MTOT / 256, EMB / 256, 3), 512, 131072, stream>>>(
        Xb, Wb, bq, bk, bv, Qb, Kb, Vtb);

    scores_8ph<<<dim3(4, 4, BATCH), 512, 131072, stream>>>(Qb, Kb, sims);

    softmax_bf16<<<dim3(MTOT), 256, 0, stream>>>(sims, attnb);

    pv_8ph<<<dim3(4, 4, BATCH), 512, 131072, stream>>>(attnb, Vtb, (float*)d_out);
}

// Round 10
// 224.956 us; speedup vs baseline: 1.0386x; 1.0386x over previous
//
#include <hip/hip_runtime.h>
#include <hip/hip_bf16.h>
#include <stdint.h>

// Masked self-attention (round 10 = round 9 resubmitted; round-9 bench died
// on infra before execution).
// qkv made PERSISTENT: 256 blocks exactly, each block sweeps z=0,1,2 at its
// (m0,n0) as one continuous 48-K-tile 8-phase pipeline (prologue/drain paid
// once, not 3x; acc dumped+zeroed at z boundaries without breaking the
// double-buffer).  All swizzles dropped (rounds 4-8: within noise, FETCH 2.7x).
// scores/softmax/pv/convert byte-identical to round 4.

#define BATCH 16
#define SEQL  1024
#define IMG   256
#define EMB   1024
#define MTOT  (BATCH * SEQL)   // 16384

typedef __attribute__((ext_vector_type(8))) short short8;
typedef __attribute__((ext_vector_type(8))) unsigned short u16x8;
typedef __attribute__((ext_vector_type(4))) unsigned short u16x4;
typedef __attribute__((ext_vector_type(4))) float f32x4;

__device__ __forceinline__ void gload_lds16(const void* g, void* l) {
    __builtin_amdgcn_global_load_lds(
        (const __attribute__((address_space(1))) void*)g,
        (__attribute__((address_space(3))) void*)l, 16, 0, 0);
}

__device__ __forceinline__ unsigned short f2bf(float f) {
    uint32_t u = __float_as_uint(f);
    u += 0x7FFFu + ((u >> 16) & 1u);
    return (unsigned short)(u >> 16);
}

// ===========================================================================
// 8-phase 256x256 GEMM core (verified rounds 3-8) — used by scores/pv.
// ===========================================================================
template<bool SWAP>
__device__ __forceinline__ void gemm8_core(
    const char* __restrict__ Ab, const char* __restrict__ Bb,
    char* lds, const int KT, f32x4 acc[8][4])
{
    const int tid  = threadIdx.x;
    const int lane = tid & 63;
    const int wv   = tid >> 6;
    const int wr   = wv >> 2, wc = wv & 3;
    const int lr   = lane & 15, kh = lane >> 4;

    const int sw  = (lr & 7) << 4;
    const int cb0 = (kh * 16) ^ sw;
    const int cb1 = (64 + kh * 16) ^ sw;

    const size_t psStage = (size_t)(wv * 16 + (lane >> 3)) * 2048
                         + (size_t)((((lane & 7) ^ (lane >> 3))) << 4);

    auto stageA = [&](int tt, int h) {
        if (tt < KT) {
            const char* s = Ab + psStage + (size_t)h * 262144 + (size_t)tt * 128;
            char* d = lds + (tt & 1) * 65536 + h * 16384 + wv * 2048;
            gload_lds16(s, d);
            gload_lds16(s + 16384, d + 1024);
        }
    };
    auto stageB = [&](int tt, int h) {
        if (tt < KT) {
            const char* s = Bb + psStage + (size_t)h * 262144 + (size_t)tt * 128;
            char* d = lds + (tt & 1) * 65536 + 32768 + h * 16384 + wv * 2048;
            gload_lds16(s, d);
            gload_lds16(s + 16384, d + 1024);
        }
    };

    stageA(0, 0); stageA(0, 1); stageB(0, 0); stageB(0, 1); stageA(1, 0);
    asm volatile("s_waitcnt vmcnt(2)" ::: "memory");
    __builtin_amdgcn_s_barrier();

    short8 af[4][2];
    short8 bf[4][2];

    const int bh   = wc >> 1;
    const int brow = (wc & 1) * 64 + lr;

    #pragma unroll 1
    for (int t = 0; t < KT; ++t) {
        const int d = t & 1;
        const char* aBase = lds + d * 65536 + wr * 16384 + lr * 128;
        const char* bBase = lds + d * 65536 + 32768 + bh * 16384 + brow * 128;

        auto loadA = [&](int IQ) {
            #pragma unroll
            for (int ii = 0; ii < 4; ++ii) {
                af[ii][0] = *(const short8*)(aBase + (IQ * 4 + ii) * 2048 + cb0);
                af[ii][1] = *(const short8*)(aBase + (IQ * 4 + ii) * 2048 + cb1);
            }
        };
        auto loadB = [&](int JQ) {
            #pragma unroll
            for (int jj = 0; jj < 2; ++jj) {
                bf[JQ * 2 + jj][0] = *(const short8*)(bBase + (JQ * 2 + jj) * 2048 + cb0);
                bf[JQ * 2 + jj][1] = *(const short8*)(bBase + (JQ * 2 + jj) * 2048 + cb1);
            }
        };
        auto mfma16 = [&](int IQ, int JQ) {
            __builtin_amdgcn_s_barrier();
            __builtin_amdgcn_s_setprio(1);
            #pragma unroll
            for (int ii = 0; ii < 4; ++ii)
                #pragma unroll
                for (int jj = 0; jj < 2; ++jj)
                    #pragma unroll
                    for (int kk = 0; kk < 2; ++kk) {
                        f32x4& c = acc[IQ * 4 + ii][JQ * 2 + jj];
                        if (SWAP)
                            c = __builtin_amdgcn_mfma_f32_16x16x32_bf16(
                                bf[JQ * 2 + jj][kk], af[ii][kk], c, 0, 0, 0);
                        else
                            c = __builtin_amdgcn_mfma_f32_16x16x32_bf16(
                                af[ii][kk], bf[JQ * 2 + jj][kk], c, 0, 0, 0);
                    }
            __builtin_amdgcn_s_setprio(0);
        };

        loadA(0); loadB(0); stageA(t + 1, 1);
        mfma16(0, 0);
        __builtin_amdgcn_s_barrier();
        loadB(1); stageB(t + 1, 0);
        mfma16(0, 1);
        __builtin_amdgcn_s_barrier();
        loadA(1); stageB(t + 1, 1);
        mfma16(1, 1);
        __builtin_amdgcn_s_barrier();
        stageA(t + 2, 0);
        mfma16(1, 0);
        if (t < KT - 2) asm volatile("s_waitcnt vmcnt(2)" ::: "memory");
        else            asm volatile("s_waitcnt vmcnt(0)" ::: "memory");
        __builtin_amdgcn_s_barrier();
    }
}

// ===========================================================================
// Persistent QKV: 256 blocks, block f owns (m0 = (f>>2)*256, n0 = (f&3)*256)
// and runs one continuous 48-K-tile pipeline: tiles [0,16) = Wq, [16,32) = Wk,
// [32,48) = Wv.  SWAP MFMA throughout; acc dumped at t=16/32 (Q,K row-major
// packed stores) and after the loop (V -> Vt[b][d][s], scalar stores).
// ===========================================================================
__global__ void __launch_bounds__(512, 1) qkv_persist(
    const unsigned short* __restrict__ Xb, const unsigned short* __restrict__ Wb,
    const float* __restrict__ bq, const float* __restrict__ bk,
    const float* __restrict__ bv,
    unsigned short* __restrict__ Qb, unsigned short* __restrict__ Kb,
    unsigned short* __restrict__ Vtb)
{
    extern __shared__ char lds[];
    const int f  = blockIdx.x;             // 0..255
    const int m0 = (f >> 2) * 256;
    const int n0 = (f & 3) * 256;

    const int tid  = threadIdx.x;
    const int lane = tid & 63;
    const int wv   = tid >> 6;
    const int wr   = wv >> 2, wc = wv & 3;
    const int lr   = lane & 15, kh = lane >> 4;

    const int sw  = (lr & 7) << 4;
    const int cb0 = (kh * 16) ^ sw;
    const int cb1 = (64 + kh * 16) ^ sw;

    const size_t psStage = (size_t)(wv * 16 + (lane >> 3)) * 2048
                         + (size_t)((((lane & 7) ^ (lane >> 3))) << 4);

    const char* Asrc = (const char*)Xb + (size_t)m0 * 2048 + psStage;
    const char* Bsrc = (const char*)Wb + (size_t)n0 * 2048 + psStage;

    auto stageA = [&](int tt, int h) {
        if (tt < 48) {
            const char* s = Asrc + (size_t)(tt & 15) * 128 + (size_t)h * 262144;
            char* d = lds + (tt & 1) * 65536 + h * 16384 + wv * 2048;
            gload_lds16(s, d);
            gload_lds16(s + 16384, d + 1024);
        }
    };
    auto stageB = [&](int tt, int h) {
        if (tt < 48) {
            const char* s = Bsrc + (size_t)(tt >> 4) * 2097152
                          + (size_t)(tt & 15) * 128 + (size_t)h * 262144;
            char* d = lds + (tt & 1) * 65536 + 32768 + h * 16384 + wv * 2048;
            gload_lds16(s, d);
            gload_lds16(s + 16384, d + 1024);
        }
    };

    f32x4 acc[8][4] = {};

    // Q/K epilogue: SWAP layout -> row = lane&15, 4 consecutive cols -> 8 B
    auto epiQK = [&](int z) {
        unsigned short* Y = z ? Kb : Qb;
        const float* bias = z ? bk : bq;
        #pragma unroll
        for (int i = 0; i < 8; ++i) {
            const int grow = m0 + wr * 128 + i * 16 + lr;
            #pragma unroll
            for (int j = 0; j < 4; ++j) {
                const int gc0 = n0 + wc * 64 + j * 16 + kh * 4;
                const float4 bb = *(const float4*)(bias + gc0);
                u16x4 o;
                o[0] = f2bf(acc[i][j][0] + bb.x);
                o[1] = f2bf(acc[i][j][1] + bb.y);
                o[2] = f2bf(acc[i][j][2] + bb.z);
                o[3] = f2bf(acc[i][j][3] + bb.w);
                *(u16x4*)(Y + (size_t)grow * EMB + gc0) = o;
            }
        }
    };

    stageA(0, 0); stageA(0, 1); stageB(0, 0); stageB(0, 1); stageA(1, 0);
    asm volatile("s_waitcnt vmcnt(2)" ::: "memory");
    __builtin_amdgcn_s_barrier();

    short8 af[4][2];
    short8 bf[4][2];

    const int bh   = wc >> 1;
    const int brow = (wc & 1) * 64 + lr;

    #pragma unroll 1
    for (int t = 0; t < 48; ++t) {
        if (t == 16 || t == 32) {               // dump finished z-sweep
            epiQK(t == 32 ? 1 : 0);
            #pragma unroll
            for (int i = 0; i < 8; ++i)
                #pragma unroll
                for (int j = 0; j < 4; ++j)
                    acc[i][j] = (f32x4){0.f, 0.f, 0.f, 0.f};
        }

        const int d = t & 1;
        const char* aBase = lds + d * 65536 + wr * 16384 + lr * 128;
        const char* bBase = lds + d * 65536 + 32768 + bh * 16384 + brow * 128;

        auto loadA = [&](int IQ) {
            #pragma unroll
            for (int ii = 0; ii < 4; ++ii) {
                af[ii][0] = *(const short8*)(aBase + (IQ * 4 + ii) * 2048 + cb0);
                af[ii][1] = *(const short8*)(aBase + (IQ * 4 + ii) * 2048 + cb1);
            }
        };
        auto loadB = [&](int JQ) {
            #pragma unroll
            for (int jj = 0; jj < 2; ++jj) {
                bf[JQ * 2 + jj][0] = *(const short8*)(bBase + (JQ * 2 + jj) * 2048 + cb0);
                bf[JQ * 2 + jj][1] = *(const short8*)(bBase + (JQ * 2 + jj) * 2048 + cb1);
            }
        };
        auto mfma16 = [&](int IQ, int JQ) {
            __builtin_amdgcn_s_barrier();
            __builtin_amdgcn_s_setprio(1);
            #pragma unroll
            for (int ii = 0; ii < 4; ++ii)
                #pragma unroll
                for (int jj = 0; jj < 2; ++jj)
                    #pragma unroll
                    for (int kk = 0; kk < 2; ++kk)
                        acc[IQ * 4 + ii][JQ * 2 + jj] =
                            __builtin_amdgcn_mfma_f32_16x16x32_bf16(
                                bf[JQ * 2 + jj][kk], af[ii][kk],
                                acc[IQ * 4 + ii][JQ * 2 + jj], 0, 0, 0);
            __builtin_amdgcn_s_setprio(0);
        };

        loadA(0); loadB(0); stageA(t + 1, 1);
        mfma16(0, 0);
        __builtin_amdgcn_s_barrier();
        loadB(1); stageB(t + 1, 0);
        mfma16(0, 1);
        __builtin_amdgcn_s_barrier();
        loadA(1); stageB(t + 1, 1);
        mfma16(1, 1);
        __builtin_amdgcn_s_barrier();
        stageA(t + 2, 0);
        mfma16(1, 0);
        if (t < 46) asm volatile("s_waitcnt vmcnt(2)" ::: "memory");
        else        asm volatile("s_waitcnt vmcnt(0)" ::: "memory");
        __builtin_amdgcn_s_barrier();
    }

    // V epilogue: SWAP layout, scatter to Vt[b][d][s] (scalar 2 B stores).
    #pragma unroll
    for (int j = 0; j < 4; ++j) {
        const int gc0 = n0 + wc * 64 + j * 16 + kh * 4;
        const float4 bb = *(const float4*)(bv + gc0);
        #pragma unroll
        for (int i = 0; i < 8; ++i) {
            const int grow = m0 + wr * 128 + i * 16 + lr;
            const int b = grow >> 10, s = grow & 1023;
            unsigned short* vp = Vtb + ((size_t)b << 20) + ((size_t)gc0 << 10) + s;
            vp[0]        = f2bf(acc[i][j][0] + bb.x);
            vp[1u << 10] = f2bf(acc[i][j][1] + bb.y);
            vp[2u << 10] = f2bf(acc[i][j][2] + bb.z);
            vp[3u << 10] = f2bf(acc[i][j][3] + bb.w);
        }
    }
}

// ---------------------------------------------------------------------------
// scores[b,q,k] = (Q.K)/32 fp32, 256^2 tiles, skip fully-masked (tj>ti).
// ---------------------------------------------------------------------------
__global__ void __launch_bounds__(512, 1) scores_8ph(
    const unsigned short* __restrict__ Qb, const unsigned short* __restrict__ Kb,
    float* __restrict__ sims)
{
    const int ti = blockIdx.x, tj = blockIdx.y, b = blockIdx.z;
    if (tj > ti) return;
    extern __shared__ char lds[];

    const size_t boff = (size_t)b << 20;
    const int m0 = ti * 256, n0 = tj * 256;
    const char* Ab = (const char*)(Qb + boff) + (size_t)m0 * 2048;
    const char* Bb = (const char*)(Kb + boff) + (size_t)n0 * 2048;

    f32x4 acc[8][4] = {};
    gemm8_core<true>(Ab, Bb, lds, 16, acc);

    float* S = sims + boff;
    const int lane = threadIdx.x & 63, wv = threadIdx.x >> 6;
    const int wr = wv >> 2, wc = wv & 3, lr = lane & 15, kh = lane >> 4;
    #pragma unroll
    for (int i = 0; i < 8; ++i) {
        const int q = m0 + wr * 128 + i * 16 + lr;
        #pragma unroll
        for (int j = 0; j < 4; ++j) {
            const int k0 = n0 + wc * 64 + j * 16 + kh * 4;
            float4 o;
            o.x = acc[i][j][0] * 0.03125f;
            o.y = acc[i][j][1] * 0.03125f;
            o.z = acc[i][j][2] * 0.03125f;
            o.w = acc[i][j][3] * 0.03125f;
            *(float4*)(S + (size_t)q * SEQL + k0) = o;
        }
    }
}

// ---------------------------------------------------------------------------
// Row softmax over valid prefix L = max(256, s+1); bf16 out zero-padded to
// Kt = max(256, 256*(s/256+1)).  Loads trimmed to c < Kt.
// ---------------------------------------------------------------------------
__global__ __launch_bounds__(256) void softmax_bf16(
    const float* __restrict__ sims, unsigned short* __restrict__ attnb)
{
    const int row = blockIdx.x;
    const int s   = row & (SEQL - 1);
    const int L   = (s + 1 > IMG) ? (s + 1) : IMG;
    const int Kt  = ((((s >> 8) + 1) << 8) > IMG) ? (((s >> 8) + 1) << 8) : IMG;

    const float* p = sims + (size_t)row * SEQL;
    const int tid = threadIdx.x, lane = tid & 63, wv = tid >> 6;
    const int c = tid * 4;
    float4 v = make_float4(0.f, 0.f, 0.f, 0.f);
    if (c < Kt) v = *(const float4*)(p + c);

    __shared__ float red[8];

    float m = -3.0e38f;
    if (c + 0 < L) m = fmaxf(m, v.x);
    if (c + 1 < L) m = fmaxf(m, v.y);
    if (c + 2 < L) m = fmaxf(m, v.z);
    if (c + 3 < L) m = fmaxf(m, v.w);
    #pragma unroll
    for (int off = 32; off > 0; off >>= 1) m = fmaxf(m, __shfl_xor(m, off));
    if (lane == 0) red[wv] = m;
    __syncthreads();
    m = fmaxf(fmaxf(red[0], red[1]), fmaxf(red[2], red[3]));

    const float e0 = (c + 0 < L) ? __expf(v.x - m) : 0.0f;
    const float e1 = (c + 1 < L) ? __expf(v.y - m) : 0.0f;
    const float e2 = (c + 2 < L) ? __expf(v.z - m) : 0.0f;
    const float e3 = (c + 3 < L) ? __expf(v.w - m) : 0.0f;
    float ssum = e0 + e1 + e2 + e3;
    #pragma unroll
    for (int off = 32; off > 0; off >>= 1) ssum += __shfl_xor(ssum, off);
    if (lane == 0) red[4 + wv] = ssum;
    __syncthreads();
    const float inv = 1.0f / (red[4] + red[5] + red[6] + red[7]);

    if (c < Kt) {
        u16x4 o;
        o[0] = f2bf(e0 * inv); o[1] = f2bf(e1 * inv);
        o[2] = f2bf(e2 * inv); o[3] = f2bf(e3 * inv);
        *(u16x4*)(attnb + (size_t)row * SEQL + c) = o;
    }
}

// ---------------------------------------------------------------------------
// out[b,q,d] = attn[b,q,:] . V[b,:,d] via B^T GEMM against Vt[b][d][k].
// 256^2 tiles, KT = (ti+1)*4.
// ---------------------------------------------------------------------------
__global__ void __launch_bounds__(512, 1) pv_8ph(
    const unsigned short* __restrict__ attnb, const unsigned short* __restrict__ Vtb,
    float* __restrict__ out)
{
    const int ti = blockIdx.x, tj = blockIdx.y, b = blockIdx.z;
    extern __shared__ char lds[];

    const size_t boff = (size_t)b << 20;
    const int m0 = ti * 256, n0 = tj * 256;
    const int KT = (ti + 1) * 4;

    const char* Ab = (const char*)(attnb + boff) + (size_t)m0 * 2048;
    const char* Bb = (const char*)(Vtb + boff) + (size_t)n0 * 2048;

    f32x4 acc[8][4] = {};
    gemm8_core<true>(Ab, Bb, lds, KT, acc);

    float* O = out + boff;
    const int lane = threadIdx.x & 63, wv = threadIdx.x >> 6;
    const int wr = wv >> 2, wc = wv & 3, lr = lane & 15, kh = lane >> 4;
    #pragma unroll
    for (int i = 0; i < 8; ++i) {
        const int q = m0 + wr * 128 + i * 16 + lr;
        #pragma unroll
        for (int j = 0; j < 4; ++j) {
            const int d0 = n0 + wc * 64 + j * 16 + kh * 4;
            *(float4*)(O + (size_t)q * EMB + d0) = *(const float4*)&acc[i][j];
        }
    }
}

// ---------------------------------------------------------------------------
// fp32 -> bf16 conversion of x and the three weight matrices.
// ---------------------------------------------------------------------------
__global__ __launch_bounds__(256) void convert_bf16(
    const float* __restrict__ x,
    const float* __restrict__ Wq, const float* __restrict__ Wk,
    const float* __restrict__ Wv,
    unsigned short* __restrict__ Xb, unsigned short* __restrict__ Wb)
{
    const size_t NE  = (size_t)MTOT * EMB;
    const size_t idx = ((size_t)blockIdx.x * 256 + threadIdx.x) * 8;
    const float* src; unsigned short* dst; size_t off;
    if (idx < NE) { src = x; dst = Xb; off = idx; }
    else {
        const size_t w = idx - NE;
        const int wi = (int)(w >> 20);
        off = w & 0xFFFFFu;
        src = (wi == 0) ? Wq : (wi == 1) ? Wk : Wv;
        dst = Wb + ((size_t)wi << 20);
    }
    const float4 a = *(const float4*)(src + off);
    const float4 b = *(const float4*)(src + off + 4);
    u16x8 o;
    o[0] = f2bf(a.x); o[1] = f2bf(a.y); o[2] = f2bf(a.z); o[3] = f2bf(a.w);
    o[4] = f2bf(b.x); o[5] = f2bf(b.y); o[6] = f2bf(b.z); o[7] = f2bf(b.w);
    *(u16x8*)(dst + off) = o;
}

// ---------------------------------------------------------------------------
extern "C" void kernel_launch(void* const* d_in, const int* in_sizes, int n_in,
                              void* d_out, int out_size, void* d_ws, size_t ws_size,
                              hipStream_t stream)
{
    const float* x  = (const float*)d_in[0];
    const float* Wq = (const float*)d_in[1];
    const float* bq = (const float*)d_in[2];
    const float* Wk = (const float*)d_in[3];
    const float* bk = (const float*)d_in[4];
    const float* Wv = (const float*)d_in[5];
    const float* bv = (const float*)d_in[6];

    const size_t NE = (size_t)MTOT * EMB;
    unsigned short* base  = (unsigned short*)d_ws;
    unsigned short* Qb    = base;                  // NE bf16
    unsigned short* Kb    = base + NE;             // NE
    unsigned short* Vtb   = base + 2 * NE;         // NE
    unsigned short* Xb    = base + 3 * NE;         // NE (dead after qkv)
    unsigned short* attnb = base + 3 * NE;         // reuses Xb region
    unsigned short* Wb    = base + 4 * NE;         // 3 * 2^20
    float* sims = (float*)d_out;

    hipFuncSetAttribute(reinterpret_cast<const void*>(qkv_persist),
                        hipFuncAttributeMaxDynamicSharedMemorySize, 131072);
    hipFuncSetAttribute(reinterpret_cast<const void*>(scores_8ph),
                        hipFuncAttributeMaxDynamicSharedMemorySize, 131072);
    hipFuncSetAttribute(reinterpret_cast<const void*>(pv_8ph),
                        hipFuncAttributeMaxDynamicSharedMemorySize, 131072);

    convert_bf16<<<dim3((unsigned)((NE + 3u * (1u << 20)) / 2048)), 256, 0, stream>>>(
        x, Wq, Wk, Wv, Xb, Wb);

    qkv_persist<<<dim3(256), 512, 131072, stream>>>(
        Xb, Wb, bq, bk, bv, Qb, Kb, Vtb);

    scores_8ph<<<dim3(4, 4, BATCH), 512, 131072, stream>>>(Qb, Kb, sims);

    softmax_bf16<<<dim3(MTOT), 256, 0, stream>>>(sims, attnb);

    pv_8ph<<<dim3(4, 4, BATCH), 512, 131072, stream>>>(attnb, Vtb, (float*)d_out);
}

// Round 11
// 218.850 us; speedup vs baseline: 1.0676x; 1.0279x over previous
//
#include <hip/hip_runtime.h>
#include <hip/hip_bf16.h>
#include <stdint.h>

// Masked self-attention (round 11).
// Round-10 pipeline with ONE change: qkv_persist block decode flipped to
// m-fastest (m0 = f&63, n0 = f>>6) so XCD round-robin keeps each W panel
// L2-resident per XCD and X streams once per z-sweep (predicted FETCH
// 203 -> ~110 MB; latency relief on the counted-vmcnt pipeline).
// scores/softmax/pv/convert byte-identical to rounds 4/10.

#define BATCH 16
#define SEQL  1024
#define IMG   256
#define EMB   1024
#define MTOT  (BATCH * SEQL)   // 16384

typedef __attribute__((ext_vector_type(8))) short short8;
typedef __attribute__((ext_vector_type(8))) unsigned short u16x8;
typedef __attribute__((ext_vector_type(4))) unsigned short u16x4;
typedef __attribute__((ext_vector_type(4))) float f32x4;

__device__ __forceinline__ void gload_lds16(const void* g, void* l) {
    __builtin_amdgcn_global_load_lds(
        (const __attribute__((address_space(1))) void*)g,
        (__attribute__((address_space(3))) void*)l, 16, 0, 0);
}

__device__ __forceinline__ unsigned short f2bf(float f) {
    uint32_t u = __float_as_uint(f);
    u += 0x7FFFu + ((u >> 16) & 1u);
    return (unsigned short)(u >> 16);
}

// ===========================================================================
// 8-phase 256x256 GEMM core (verified rounds 3-10) — used by scores/pv.
// ===========================================================================
template<bool SWAP>
__device__ __forceinline__ void gemm8_core(
    const char* __restrict__ Ab, const char* __restrict__ Bb,
    char* lds, const int KT, f32x4 acc[8][4])
{
    const int tid  = threadIdx.x;
    const int lane = tid & 63;
    const int wv   = tid >> 6;
    const int wr   = wv >> 2, wc = wv & 3;
    const int lr   = lane & 15, kh = lane >> 4;

    const int sw  = (lr & 7) << 4;
    const int cb0 = (kh * 16) ^ sw;
    const int cb1 = (64 + kh * 16) ^ sw;

    const size_t psStage = (size_t)(wv * 16 + (lane >> 3)) * 2048
                         + (size_t)((((lane & 7) ^ (lane >> 3))) << 4);

    auto stageA = [&](int tt, int h) {
        if (tt < KT) {
            const char* s = Ab + psStage + (size_t)h * 262144 + (size_t)tt * 128;
            char* d = lds + (tt & 1) * 65536 + h * 16384 + wv * 2048;
            gload_lds16(s, d);
            gload_lds16(s + 16384, d + 1024);
        }
    };
    auto stageB = [&](int tt, int h) {
        if (tt < KT) {
            const char* s = Bb + psStage + (size_t)h * 262144 + (size_t)tt * 128;
            char* d = lds + (tt & 1) * 65536 + 32768 + h * 16384 + wv * 2048;
            gload_lds16(s, d);
            gload_lds16(s + 16384, d + 1024);
        }
    };

    stageA(0, 0); stageA(0, 1); stageB(0, 0); stageB(0, 1); stageA(1, 0);
    asm volatile("s_waitcnt vmcnt(2)" ::: "memory");
    __builtin_amdgcn_s_barrier();

    short8 af[4][2];
    short8 bf[4][2];

    const int bh   = wc >> 1;
    const int brow = (wc & 1) * 64 + lr;

    #pragma unroll 1
    for (int t = 0; t < KT; ++t) {
        const int d = t & 1;
        const char* aBase = lds + d * 65536 + wr * 16384 + lr * 128;
        const char* bBase = lds + d * 65536 + 32768 + bh * 16384 + brow * 128;

        auto loadA = [&](int IQ) {
            #pragma unroll
            for (int ii = 0; ii < 4; ++ii) {
                af[ii][0] = *(const short8*)(aBase + (IQ * 4 + ii) * 2048 + cb0);
                af[ii][1] = *(const short8*)(aBase + (IQ * 4 + ii) * 2048 + cb1);
            }
        };
        auto loadB = [&](int JQ) {
            #pragma unroll
            for (int jj = 0; jj < 2; ++jj) {
                bf[JQ * 2 + jj][0] = *(const short8*)(bBase + (JQ * 2 + jj) * 2048 + cb0);
                bf[JQ * 2 + jj][1] = *(const short8*)(bBase + (JQ * 2 + jj) * 2048 + cb1);
            }
        };
        auto mfma16 = [&](int IQ, int JQ) {
            __builtin_amdgcn_s_barrier();
            __builtin_amdgcn_s_setprio(1);
            #pragma unroll
            for (int ii = 0; ii < 4; ++ii)
                #pragma unroll
                for (int jj = 0; jj < 2; ++jj)
                    #pragma unroll
                    for (int kk = 0; kk < 2; ++kk) {
                        f32x4& c = acc[IQ * 4 + ii][JQ * 2 + jj];
                        if (SWAP)
                            c = __builtin_amdgcn_mfma_f32_16x16x32_bf16(
                                bf[JQ * 2 + jj][kk], af[ii][kk], c, 0, 0, 0);
                        else
                            c = __builtin_amdgcn_mfma_f32_16x16x32_bf16(
                                af[ii][kk], bf[JQ * 2 + jj][kk], c, 0, 0, 0);
                    }
            __builtin_amdgcn_s_setprio(0);
        };

        loadA(0); loadB(0); stageA(t + 1, 1);
        mfma16(0, 0);
        __builtin_amdgcn_s_barrier();
        loadB(1); stageB(t + 1, 0);
        mfma16(0, 1);
        __builtin_amdgcn_s_barrier();
        loadA(1); stageB(t + 1, 1);
        mfma16(1, 1);
        __builtin_amdgcn_s_barrier();
        stageA(t + 2, 0);
        mfma16(1, 0);
        if (t < KT - 2) asm volatile("s_waitcnt vmcnt(2)" ::: "memory");
        else            asm volatile("s_waitcnt vmcnt(0)" ::: "memory");
        __builtin_amdgcn_s_barrier();
    }
}

// ===========================================================================
// Persistent QKV: 256 blocks, m-fastest decode (m0 = f&63, n0 = f>>6) so
// XCD round-robin groups blocks sharing the W panel.  Each block sweeps
// z=0,1,2 at its (m0,n0) as one continuous 48-K-tile 8-phase pipeline.
// ===========================================================================
__global__ void __launch_bounds__(512, 1) qkv_persist(
    const unsigned short* __restrict__ Xb, const unsigned short* __restrict__ Wb,
    const float* __restrict__ bq, const float* __restrict__ bk,
    const float* __restrict__ bv,
    unsigned short* __restrict__ Qb, unsigned short* __restrict__ Kb,
    unsigned short* __restrict__ Vtb)
{
    extern __shared__ char lds[];
    const int f  = blockIdx.x;             // 0..255
    const int m0 = (f & 63) * 256;         // m-fastest: A panel varies with f
    const int n0 = (f >> 6) * 256;         // W panel shared by 64 consecutive f

    const int tid  = threadIdx.x;
    const int lane = tid & 63;
    const int wv   = tid >> 6;
    const int wr   = wv >> 2, wc = wv & 3;
    const int lr   = lane & 15, kh = lane >> 4;

    const int sw  = (lr & 7) << 4;
    const int cb0 = (kh * 16) ^ sw;
    const int cb1 = (64 + kh * 16) ^ sw;

    const size_t psStage = (size_t)(wv * 16 + (lane >> 3)) * 2048
                         + (size_t)((((lane & 7) ^ (lane >> 3))) << 4);

    const char* Asrc = (const char*)Xb + (size_t)m0 * 2048 + psStage;
    const char* Bsrc = (const char*)Wb + (size_t)n0 * 2048 + psStage;

    auto stageA = [&](int tt, int h) {
        if (tt < 48) {
            const char* s = Asrc + (size_t)(tt & 15) * 128 + (size_t)h * 262144;
            char* d = lds + (tt & 1) * 65536 + h * 16384 + wv * 2048;
            gload_lds16(s, d);
            gload_lds16(s + 16384, d + 1024);
        }
    };
    auto stageB = [&](int tt, int h) {
        if (tt < 48) {
            const char* s = Bsrc + (size_t)(tt >> 4) * 2097152
                          + (size_t)(tt & 15) * 128 + (size_t)h * 262144;
            char* d = lds + (tt & 1) * 65536 + 32768 + h * 16384 + wv * 2048;
            gload_lds16(s, d);
            gload_lds16(s + 16384, d + 1024);
        }
    };

    f32x4 acc[8][4] = {};

    // Q/K epilogue: SWAP layout -> row = lane&15, 4 consecutive cols -> 8 B
    auto epiQK = [&](int z) {
        unsigned short* Y = z ? Kb : Qb;
        const float* bias = z ? bk : bq;
        #pragma unroll
        for (int i = 0; i < 8; ++i) {
            const int grow = m0 + wr * 128 + i * 16 + lr;
            #pragma unroll
            for (int j = 0; j < 4; ++j) {
                const int gc0 = n0 + wc * 64 + j * 16 + kh * 4;
                const float4 bb = *(const float4*)(bias + gc0);
                u16x4 o;
                o[0] = f2bf(acc[i][j][0] + bb.x);
                o[1] = f2bf(acc[i][j][1] + bb.y);
                o[2] = f2bf(acc[i][j][2] + bb.z);
                o[3] = f2bf(acc[i][j][3] + bb.w);
                *(u16x4*)(Y + (size_t)grow * EMB + gc0) = o;
            }
        }
    };

    stageA(0, 0); stageA(0, 1); stageB(0, 0); stageB(0, 1); stageA(1, 0);
    asm volatile("s_waitcnt vmcnt(2)" ::: "memory");
    __builtin_amdgcn_s_barrier();

    short8 af[4][2];
    short8 bf[4][2];

    const int bh   = wc >> 1;
    const int brow = (wc & 1) * 64 + lr;

    #pragma unroll 1
    for (int t = 0; t < 48; ++t) {
        if (t == 16 || t == 32) {               // dump finished z-sweep
            epiQK(t == 32 ? 1 : 0);
            #pragma unroll
            for (int i = 0; i < 8; ++i)
                #pragma unroll
                for (int j = 0; j < 4; ++j)
                    acc[i][j] = (f32x4){0.f, 0.f, 0.f, 0.f};
        }

        const int d = t & 1;
        const char* aBase = lds + d * 65536 + wr * 16384 + lr * 128;
        const char* bBase = lds + d * 65536 + 32768 + bh * 16384 + brow * 128;

        auto loadA = [&](int IQ) {
            #pragma unroll
            for (int ii = 0; ii < 4; ++ii) {
                af[ii][0] = *(const short8*)(aBase + (IQ * 4 + ii) * 2048 + cb0);
                af[ii][1] = *(const short8*)(aBase + (IQ * 4 + ii) * 2048 + cb1);
            }
        };
        auto loadB = [&](int JQ) {
            #pragma unroll
            for (int jj = 0; jj < 2; ++jj) {
                bf[JQ * 2 + jj][0] = *(const short8*)(bBase + (JQ * 2 + jj) * 2048 + cb0);
                bf[JQ * 2 + jj][1] = *(const short8*)(bBase + (JQ * 2 + jj) * 2048 + cb1);
            }
        };
        auto mfma16 = [&](int IQ, int JQ) {
            __builtin_amdgcn_s_barrier();
            __builtin_amdgcn_s_setprio(1);
            #pragma unroll
            for (int ii = 0; ii < 4; ++ii)
                #pragma unroll
                for (int jj = 0; jj < 2; ++jj)
                    #pragma unroll
                    for (int kk = 0; kk < 2; ++kk)
                        acc[IQ * 4 + ii][JQ * 2 + jj] =
                            __builtin_amdgcn_mfma_f32_16x16x32_bf16(
                                bf[JQ * 2 + jj][kk], af[ii][kk],
                                acc[IQ * 4 + ii][JQ * 2 + jj], 0, 0, 0);
            __builtin_amdgcn_s_setprio(0);
        };

        loadA(0); loadB(0); stageA(t + 1, 1);
        mfma16(0, 0);
        __builtin_amdgcn_s_barrier();
        loadB(1); stageB(t + 1, 0);
        mfma16(0, 1);
        __builtin_amdgcn_s_barrier();
        loadA(1); stageB(t + 1, 1);
        mfma16(1, 1);
        __builtin_amdgcn_s_barrier();
        stageA(t + 2, 0);
        mfma16(1, 0);
        if (t < 46) asm volatile("s_waitcnt vmcnt(2)" ::: "memory");
        else        asm volatile("s_waitcnt vmcnt(0)" ::: "memory");
        __builtin_amdgcn_s_barrier();
    }

    // V epilogue: SWAP layout, scatter to Vt[b][d][s] (scalar 2 B stores).
    #pragma unroll
    for (int j = 0; j < 4; ++j) {
        const int gc0 = n0 + wc * 64 + j * 16 + kh * 4;
        const float4 bb = *(const float4*)(bv + gc0);
        #pragma unroll
        for (int i = 0; i < 8; ++i) {
            const int grow = m0 + wr * 128 + i * 16 + lr;
            const int b = grow >> 10, s = grow & 1023;
            unsigned short* vp = Vtb + ((size_t)b << 20) + ((size_t)gc0 << 10) + s;
            vp[0]        = f2bf(acc[i][j][0] + bb.x);
            vp[1u << 10] = f2bf(acc[i][j][1] + bb.y);
            vp[2u << 10] = f2bf(acc[i][j][2] + bb.z);
            vp[3u << 10] = f2bf(acc[i][j][3] + bb.w);
        }
    }
}

// ---------------------------------------------------------------------------
// scores[b,q,k] = (Q.K)/32 fp32, 256^2 tiles, skip fully-masked (tj>ti).
// ---------------------------------------------------------------------------
__global__ void __launch_bounds__(512, 1) scores_8ph(
    const unsigned short* __restrict__ Qb, const unsigned short* __restrict__ Kb,
    float* __restrict__ sims)
{
    const int ti = blockIdx.x, tj = blockIdx.y, b = blockIdx.z;
    if (tj > ti) return;
    extern __shared__ char lds[];

    const size_t boff = (size_t)b << 20;
    const int m0 = ti * 256, n0 = tj * 256;
    const char* Ab = (const char*)(Qb + boff) + (size_t)m0 * 2048;
    const char* Bb = (const char*)(Kb + boff) + (size_t)n0 * 2048;

    f32x4 acc[8][4] = {};
    gemm8_core<true>(Ab, Bb, lds, 16, acc);

    float* S = sims + boff;
    const int lane = threadIdx.x & 63, wv = threadIdx.x >> 6;
    const int wr = wv >> 2, wc = wv & 3, lr = lane & 15, kh = lane >> 4;
    #pragma unroll
    for (int i = 0; i < 8; ++i) {
        const int q = m0 + wr * 128 + i * 16 + lr;
        #pragma unroll
        for (int j = 0; j < 4; ++j) {
            const int k0 = n0 + wc * 64 + j * 16 + kh * 4;
            float4 o;
            o.x = acc[i][j][0] * 0.03125f;
            o.y = acc[i][j][1] * 0.03125f;
            o.z = acc[i][j][2] * 0.03125f;
            o.w = acc[i][j][3] * 0.03125f;
            *(float4*)(S + (size_t)q * SEQL + k0) = o;
        }
    }
}

// ---------------------------------------------------------------------------
// Row softmax over valid prefix L = max(256, s+1); bf16 out zero-padded to
// Kt = max(256, 256*(s/256+1)).  Loads trimmed to c < Kt.
// ---------------------------------------------------------------------------
__global__ __launch_bounds__(256) void softmax_bf16(
    const float* __restrict__ sims, unsigned short* __restrict__ attnb)
{
    const int row = blockIdx.x;
    const int s   = row & (SEQL - 1);
    const int L   = (s + 1 > IMG) ? (s + 1) : IMG;
    const int Kt  = ((((s >> 8) + 1) << 8) > IMG) ? (((s >> 8) + 1) << 8) : IMG;

    const float* p = sims + (size_t)row * SEQL;
    const int tid = threadIdx.x, lane = tid & 63, wv = tid >> 6;
    const int c = tid * 4;
    float4 v = make_float4(0.f, 0.f, 0.f, 0.f);
    if (c < Kt) v = *(const float4*)(p + c);

    __shared__ float red[8];

    float m = -3.0e38f;
    if (c + 0 < L) m = fmaxf(m, v.x);
    if (c + 1 < L) m = fmaxf(m, v.y);
    if (c + 2 < L) m = fmaxf(m, v.z);
    if (c + 3 < L) m = fmaxf(m, v.w);
    #pragma unroll
    for (int off = 32; off > 0; off >>= 1) m = fmaxf(m, __shfl_xor(m, off));
    if (lane == 0) red[wv] = m;
    __syncthreads();
    m = fmaxf(fmaxf(red[0], red[1]), fmaxf(red[2], red[3]));

    const float e0 = (c + 0 < L) ? __expf(v.x - m) : 0.0f;
    const float e1 = (c + 1 < L) ? __expf(v.y - m) : 0.0f;
    const float e2 = (c + 2 < L) ? __expf(v.z - m) : 0.0f;
    const float e3 = (c + 3 < L) ? __expf(v.w - m) : 0.0f;
    float ssum = e0 + e1 + e2 + e3;
    #pragma unroll
    for (int off = 32; off > 0; off >>= 1) ssum += __shfl_xor(ssum, off);
    if (lane == 0) red[4 + wv] = ssum;
    __syncthreads();
    const float inv = 1.0f / (red[4] + red[5] + red[6] + red[7]);

    if (c < Kt) {
        u16x4 o;
        o[0] = f2bf(e0 * inv); o[1] = f2bf(e1 * inv);
        o[2] = f2bf(e2 * inv); o[3] = f2bf(e3 * inv);
        *(u16x4*)(attnb + (size_t)row * SEQL + c) = o;
    }
}

// ---------------------------------------------------------------------------
// out[b,q,d] = attn[b,q,:] . V[b,:,d] via B^T GEMM against Vt[b][d][k].
// 256^2 tiles, KT = (ti+1)*4.
// ---------------------------------------------------------------------------
__global__ void __launch_bounds__(512, 1) pv_8ph(
    const unsigned short* __restrict__ attnb, const unsigned short* __restrict__ Vtb,
    float* __restrict__ out)
{
    const int ti = blockIdx.x, tj = blockIdx.y, b = blockIdx.z;
    extern __shared__ char lds[];

    const size_t boff = (size_t)b << 20;
    const int m0 = ti * 256, n0 = tj * 256;
    const int KT = (ti + 1) * 4;

    const char* Ab = (const char*)(attnb + boff) + (size_t)m0 * 2048;
    const char* Bb = (const char*)(Vtb + boff) + (size_t)n0 * 2048;

    f32x4 acc[8][4] = {};
    gemm8_core<true>(Ab, Bb, lds, KT, acc);

    float* O = out + boff;
    const int lane = threadIdx.x & 63, wv = threadIdx.x >> 6;
    const int wr = wv >> 2, wc = wv & 3, lr = lane & 15, kh = lane >> 4;
    #pragma unroll
    for (int i = 0; i < 8; ++i) {
        const int q = m0 + wr * 128 + i * 16 + lr;
        #pragma unroll
        for (int j = 0; j < 4; ++j) {
            const int d0 = n0 + wc * 64 + j * 16 + kh * 4;
            *(float4*)(O + (size_t)q * EMB + d0) = *(const float4*)&acc[i][j];
        }
    }
}

// ---------------------------------------------------------------------------
// fp32 -> bf16 conversion of x and the three weight matrices.
// ---------------------------------------------------------------------------
__global__ __launch_bounds__(256) void convert_bf16(
    const float* __restrict__ x,
    const float* __restrict__ Wq, const float* __restrict__ Wk,
    const float* __restrict__ Wv,
    unsigned short* __restrict__ Xb, unsigned short* __restrict__ Wb)
{
    const size_t NE  = (size_t)MTOT * EMB;
    const size_t idx = ((size_t)blockIdx.x * 256 + threadIdx.x) * 8;
    const float* src; unsigned short* dst; size_t off;
    if (idx < NE) { src = x; dst = Xb; off = idx; }
    else {
        const size_t w = idx - NE;
        const int wi = (int)(w >> 20);
        off = w & 0xFFFFFu;
        src = (wi == 0) ? Wq : (wi == 1) ? Wk : Wv;
        dst = Wb + ((size_t)wi << 20);
    }
    const float4 a = *(const float4*)(src + off);
    const float4 b = *(const float4*)(src + off + 4);
    u16x8 o;
    o[0] = f2bf(a.x); o[1] = f2bf(a.y); o[2] = f2bf(a.z); o[3] = f2bf(a.w);
    o[4] = f2bf(b.x); o[5] = f2bf(b.y); o[6] = f2bf(b.z); o[7] = f2bf(b.w);
    *(u16x8*)(dst + off) = o;
}

// ---------------------------------------------------------------------------
extern "C" void kernel_launch(void* const* d_in, const int* in_sizes, int n_in,
                              void* d_out, int out_size, void* d_ws, size_t ws_size,
                              hipStream_t stream)
{
    const float* x  = (const float*)d_in[0];
    const float* Wq = (const float*)d_in[1];
    const float* bq = (const float*)d_in[2];
    const float* Wk = (const float*)d_in[3];
    const float* bk = (const float*)d_in[4];
    const float* Wv = (const float*)d_in[5];
    const float* bv = (const float*)d_in[6];

    const size_t NE = (size_t)MTOT * EMB;
    unsigned short* base  = (unsigned short*)d_ws;
    unsigned short* Qb    = base;                  // NE bf16
    unsigned short* Kb    = base + NE;             // NE
    unsigned short* Vtb   = base + 2 * NE;         // NE
    unsigned short* Xb    = base + 3 * NE;         // NE (dead after qkv)
    unsigned short* attnb = base + 3 * NE;         // reuses Xb region
    unsigned short* Wb    = base + 4 * NE;         // 3 * 2^20
    float* sims = (float*)d_out;

    hipFuncSetAttribute(reinterpret_cast<const void*>(qkv_persist),
                        hipFuncAttributeMaxDynamicSharedMemorySize, 131072);
    hipFuncSetAttribute(reinterpret_cast<const void*>(scores_8ph),
                        hipFuncAttributeMaxDynamicSharedMemorySize, 131072);
    hipFuncSetAttribute(reinterpret_cast<const void*>(pv_8ph),
                        hipFuncAttributeMaxDynamicSharedMemorySize, 131072);

    convert_bf16<<<dim3((unsigned)((NE + 3u * (1u << 20)) / 2048)), 256, 0, stream>>>(
        x, Wq, Wk, Wv, Xb, Wb);

    qkv_persist<<<dim3(256), 512, 131072, stream>>>(
        Xb, Wb, bq, bk, bv, Qb, Kb, Vtb);

    scores_8ph<<<dim3(4, 4, BATCH), 512, 131072, stream>>>(Qb, Kb, sims);

    softmax_bf16<<<dim3(MTOT), 256, 0, stream>>>(sims, attnb);

    pv_8ph<<<dim3(4, 4, BATCH), 512, 131072, stream>>>(attnb, Vtb, (float*)d_out);
}